// Round 3
// baseline (667.143 us; speedup 1.0000x reference)
//
#include <hip/hip_runtime.h>

// ---------------------------------------------------------------------------
// GAT_L3: 3x (GATConv -> BatchNorm -> ReLU), N=50000, E=800000 (+N self-loops).
// Round 3: alpha precomputed per edge and packed with src index (16B slot);
// gather kernel is a pure unrolled FMA-gather (round-2 node_agg recomputed
// exp on every lane and was latency-bound: 12.7% HBM, VALUBusy 37%).
// Attention dots fused into GEMM epilogue; BN is atomic-free two-stage.
// ---------------------------------------------------------------------------

__device__ __forceinline__ float lrelu(float x) { return x > 0.f ? x : 0.2f * x; }

// ---------------------------------------------------------------------------
// GEMM + attention epilogue. Thread = (8-node group) x (1 output feature j).
// A wave's 32-lane segment holds all j of one head for the same nodes, so
// es/ed = dot(h_row, a_vec) reduces with 32-wide butterflies in-register.
// ---------------------------------------------------------------------------
template <int K, int OUTF, int H>
__global__ __launch_bounds__(256) void gemm_attn_k(
    const float* __restrict__ in, const float* __restrict__ W,
    const float* __restrict__ a_src, const float* __restrict__ a_dst,
    float* __restrict__ h, float* __restrict__ es, float* __restrict__ ed,
    int N)
{
    constexpr int NPG = 8;
    int t = blockIdx.x * 256 + threadIdx.x;
    int grp = t / OUTF;
    int j = t - grp * OUTF;
    int n0 = grp * NPG;
    if (n0 >= N) return;

    const float* rows[NPG];
#pragma unroll
    for (int i = 0; i < NPG; ++i) {
        int n = n0 + i;
        if (n >= N) n = N - 1;
        rows[i] = in + (size_t)n * K;
    }
    float acc[NPG];
#pragma unroll
    for (int i = 0; i < NPG; ++i) acc[i] = 0.f;

    for (int k = 0; k < K; k += 4) {
        float w0 = W[(k + 0) * OUTF + j];
        float w1 = W[(k + 1) * OUTF + j];
        float w2 = W[(k + 2) * OUTF + j];
        float w3 = W[(k + 3) * OUTF + j];
#pragma unroll
        for (int i = 0; i < NPG; ++i) {
            float4 v = *(const float4*)(rows[i] + k);
            acc[i] += v.x * w0 + v.y * w1 + v.z * w2 + v.w * w3;
        }
    }

    float asj = a_src[j], adj = a_dst[j];
#pragma unroll
    for (int i = 0; i < NPG; ++i) {
        int n = n0 + i;
        if (n < N) h[(size_t)n * OUTF + j] = acc[i];
        float p = acc[i] * asj, q = acc[i] * adj;
#pragma unroll
        for (int m = 16; m; m >>= 1) {
            p += __shfl_xor(p, m, 32);
            q += __shfl_xor(q, m, 32);
        }
        if ((j & 31) == 0 && n < N) {
            int head = j >> 5;   // 0 when OUTF==32
            es[n * H + head] = p;
            ed[n * H + head] = q;
        }
    }
}

// ---------------------------------------------------------------------------
// CSR build: degree histogram -> two-level exclusive scan -> scatter.
// ---------------------------------------------------------------------------
__global__ __launch_bounds__(256) void deg_k(
    const int* __restrict__ ei, int* __restrict__ deg, int E, int N)
{
    int e = blockIdx.x * 256 + threadIdx.x;
    int Et = E + N;
    if (e >= Et) return;
    int d = (e < E) ? ei[E + e] : e - E;
    atomicAdd(&deg[d], 1);
}

__global__ __launch_bounds__(256) void scan1_k(
    const int* __restrict__ deg, int* __restrict__ rowtmp,
    int* __restrict__ bsum, int N)
{
    __shared__ int ls[256];
    int i = blockIdx.x * 256 + threadIdx.x;
    int v = (i < N) ? deg[i] : 0;
    int x = v;
    ls[threadIdx.x] = x;
    __syncthreads();
#pragma unroll
    for (int ofs = 1; ofs < 256; ofs <<= 1) {
        int y = (threadIdx.x >= ofs) ? ls[threadIdx.x - ofs] : 0;
        __syncthreads();
        x += y;
        ls[threadIdx.x] = x;
        __syncthreads();
    }
    if (i < N) rowtmp[i] = x - v;
    if (threadIdx.x == 255) bsum[blockIdx.x] = x;
}

__global__ __launch_bounds__(256) void scan2_k(
    const int* __restrict__ bsum, int* __restrict__ boff, int nb)
{
    __shared__ int ls[256];
    int i = threadIdx.x;
    int v = (i < nb) ? bsum[i] : 0;
    int x = v;
    ls[i] = x;
    __syncthreads();
#pragma unroll
    for (int ofs = 1; ofs < 256; ofs <<= 1) {
        int y = (i >= ofs) ? ls[i - ofs] : 0;
        __syncthreads();
        x += y;
        ls[i] = x;
        __syncthreads();
    }
    if (i < nb) boff[i] = x - v;
}

__global__ __launch_bounds__(256) void scan3_k(
    const int* __restrict__ rowtmp, const int* __restrict__ boff,
    int* __restrict__ rowptr, int N, int Et)
{
    int i = blockIdx.x * 256 + threadIdx.x;
    if (i < N) rowptr[i] = rowtmp[i] + boff[blockIdx.x];
    if (i == 0) rowptr[N] = Et;
}

__global__ __launch_bounds__(256) void scatter_k(
    const int* __restrict__ ei, const int* __restrict__ rowptr,
    int* __restrict__ cur, int* __restrict__ col, int E, int N)
{
    int e = blockIdx.x * 256 + threadIdx.x;
    int Et = E + N;
    if (e >= Et) return;
    int s, d;
    if (e < E) { s = ei[e]; d = ei[E + e]; } else { s = e - E; d = s; }
    int pos = atomicAdd(&cur[d], 1);
    col[rowptr[d] + pos] = s;
}

// ---------------------------------------------------------------------------
// Node softmax: per-node per-head max + exp-sum, then write packed slots:
//   H==2: float4 {src_bits, alpha0, alpha1, 0}   H==1: float2 {src_bits, alpha}
// First F edges of each node cached in registers (deg avg 17 < F), so the
// common case does ONE col/es gather per slot.
// ---------------------------------------------------------------------------
template <int H>
__global__ __launch_bounds__(256) void node_softmax_k(
    const int* __restrict__ rowptr, const int* __restrict__ col,
    const float* __restrict__ es, const float* __restrict__ ed,
    float4* __restrict__ pk4, float2* __restrict__ pk2, int N)
{
    constexpr int F = H * 32;
    int t = blockIdx.x * 256 + threadIdx.x;
    int node = t / F;
    int lane = t - node * F;
    if (node >= N) return;
    int base = rowptr[node];
    int deg = rowptr[node + 1] - base;

    float ed0 = ed[node * H + 0];
    float ed1 = (H == 2) ? ed[node * H + 1] : 0.f;
    const float2* es2 = (const float2*)es;

    bool have = lane < deg;
    int sc_ = 0;
    float l0c = -1e30f, l1c = -1e30f;
    if (have) {
        sc_ = col[base + lane];
        if (H == 2) {
            float2 v = es2[sc_];
            l0c = lrelu(v.x + ed0);
            l1c = lrelu(v.y + ed1);
        } else {
            l0c = lrelu(es[sc_] + ed0);
        }
    }
    float mx0 = l0c, mx1 = l1c;
    for (int e = lane + F; e < deg; e += F) {
        int s = col[base + e];
        if (H == 2) {
            float2 v = es2[s];
            mx0 = fmaxf(mx0, lrelu(v.x + ed0));
            mx1 = fmaxf(mx1, lrelu(v.y + ed1));
        } else {
            mx0 = fmaxf(mx0, lrelu(es[s] + ed0));
        }
    }
#pragma unroll
    for (int m = F / 2; m; m >>= 1) {
        mx0 = fmaxf(mx0, __shfl_xor(mx0, m, F));
        if (H == 2) mx1 = fmaxf(mx1, __shfl_xor(mx1, m, F));
    }
    float s0 = have ? __expf(l0c - mx0) : 0.f;
    float s1 = (H == 2 && have) ? __expf(l1c - mx1) : 0.f;
    for (int e = lane + F; e < deg; e += F) {
        int s = col[base + e];
        if (H == 2) {
            float2 v = es2[s];
            s0 += __expf(lrelu(v.x + ed0) - mx0);
            s1 += __expf(lrelu(v.y + ed1) - mx1);
        } else {
            s0 += __expf(lrelu(es[s] + ed0) - mx0);
        }
    }
#pragma unroll
    for (int m = F / 2; m; m >>= 1) {
        s0 += __shfl_xor(s0, m, F);
        if (H == 2) s1 += __shfl_xor(s1, m, F);
    }
    float rd0 = 1.f / (s0 + 1e-16f);
    float rd1 = (H == 2) ? 1.f / (s1 + 1e-16f) : 0.f;

    if (have) {
        if (H == 2)
            pk4[base + lane] = make_float4(__int_as_float(sc_),
                                           __expf(l0c - mx0) * rd0,
                                           __expf(l1c - mx1) * rd1, 0.f);
        else
            pk2[base + lane] = make_float2(__int_as_float(sc_),
                                           __expf(l0c - mx0) * rd0);
    }
    for (int e = lane + F; e < deg; e += F) {
        int s = col[base + e];
        if (H == 2) {
            float2 v = es2[s];
            pk4[base + e] = make_float4(__int_as_float(s),
                                        __expf(lrelu(v.x + ed0) - mx0) * rd0,
                                        __expf(lrelu(v.y + ed1) - mx1) * rd1, 0.f);
        } else {
            pk2[base + e] = make_float2(__int_as_float(s),
                                        __expf(lrelu(es[s] + ed0) - mx0) * rd0);
        }
    }
}

// ---------------------------------------------------------------------------
// Gather: out[n,f] = sum_e alpha[e] * h[src_e, f]. Pure FMA inner loop,
// x4 unrolled -> 8 independent loads in flight per iteration.
// ---------------------------------------------------------------------------
template <int H>
__global__ __launch_bounds__(256) void node_gather_k(
    const int* __restrict__ rowptr, const float4* __restrict__ pk4,
    const float2* __restrict__ pk2, const float* __restrict__ h,
    float* __restrict__ out, int N)
{
    constexpr int F = H * 32;
    int t = blockIdx.x * 256 + threadIdx.x;
    int node = t / F;
    int lane = t - node * F;
    if (node >= N) return;
    int base = rowptr[node];
    int deg = rowptr[node + 1] - base;

    float acc = 0.f;
    int e = 0;
    if (H == 2) {
        bool hi = lane >= 32;
        const float4* p = pk4 + base;
        for (; e + 4 <= deg; e += 4) {
            float4 q0 = p[e], q1 = p[e + 1], q2 = p[e + 2], q3 = p[e + 3];
            int s0 = __float_as_int(q0.x), s1 = __float_as_int(q1.x);
            int s2 = __float_as_int(q2.x), s3 = __float_as_int(q3.x);
            float a0 = hi ? q0.z : q0.y, a1 = hi ? q1.z : q1.y;
            float a2 = hi ? q2.z : q2.y, a3 = hi ? q3.z : q3.y;
            float h0 = h[(size_t)s0 * F + lane];
            float h1 = h[(size_t)s1 * F + lane];
            float h2 = h[(size_t)s2 * F + lane];
            float h3 = h[(size_t)s3 * F + lane];
            acc += a0 * h0 + a1 * h1 + a2 * h2 + a3 * h3;
        }
        for (; e < deg; ++e) {
            float4 q = p[e];
            acc += (hi ? q.z : q.y) * h[(size_t)__float_as_int(q.x) * F + lane];
        }
    } else {
        const float2* p = pk2 + base;
        for (; e + 4 <= deg; e += 4) {
            float2 q0 = p[e], q1 = p[e + 1], q2 = p[e + 2], q3 = p[e + 3];
            float h0 = h[(size_t)__float_as_int(q0.x) * F + lane];
            float h1 = h[(size_t)__float_as_int(q1.x) * F + lane];
            float h2 = h[(size_t)__float_as_int(q2.x) * F + lane];
            float h3 = h[(size_t)__float_as_int(q3.x) * F + lane];
            acc += q0.y * h0 + q1.y * h1 + q2.y * h2 + q3.y * h3;
        }
        for (; e < deg; ++e) {
            float2 q = p[e];
            acc += q.y * h[(size_t)__float_as_int(q.x) * F + lane];
        }
    }
    out[(size_t)node * F + lane] = acc;
}

// ---------------------------------------------------------------------------
// BN: atomic-free two-stage stats, then scale/shift finalize.
// ---------------------------------------------------------------------------
template <int F>
__global__ __launch_bounds__(256) void bn_stats_k(
    const float* __restrict__ x, float* __restrict__ psum,
    float* __restrict__ psumsq, int N)
{
    constexpr int RG = 256 / F;
    int f = threadIdx.x & (F - 1);
    int r = threadIdx.x / F;
    float s = 0.f, s2 = 0.f;
    for (int n = blockIdx.x * RG + r; n < N; n += gridDim.x * RG) {
        float v = x[(size_t)n * F + f];
        s += v;
        s2 += v * v;
    }
    __shared__ float ls[256], ls2[256];
    ls[threadIdx.x] = s;
    ls2[threadIdx.x] = s2;
    __syncthreads();
    if (threadIdx.x < F) {
#pragma unroll
        for (int g = 1; g < RG; ++g) { s += ls[g * F + f]; s2 += ls2[g * F + f]; }
        psum[blockIdx.x * F + f] = s;
        psumsq[blockIdx.x * F + f] = s2;
    }
}

__global__ void bn_final_k(const float* __restrict__ psum,
                           const float* __restrict__ psumsq,
                           const float* __restrict__ gamma,
                           const float* __restrict__ beta,
                           float* __restrict__ scale, float* __restrict__ shift,
                           int N, int F, int NB)
{
    int f = threadIdx.x;
    if (f >= F) return;
    float s = 0.f, s2 = 0.f;
    for (int b = 0; b < NB; ++b) { s += psum[b * F + f]; s2 += psumsq[b * F + f]; }
    float inv = 1.f / (float)N;
    float mu = s * inv;
    float var = s2 * inv - mu * mu;
    var = fmaxf(var, 0.f);
    float rs = rsqrtf(var + 1e-5f);
    float sc = rs * gamma[f];
    scale[f] = sc;
    shift[f] = beta[f] - mu * sc;
}

// In-place BN-apply + ReLU (float4 vectorized; 4 | F so f pattern is exact).
template <int F>
__global__ __launch_bounds__(256) void norm_relu_k(
    float* __restrict__ x, const float* __restrict__ sc,
    const float* __restrict__ sh, int total4)
{
    int i = blockIdx.x * 256 + threadIdx.x;
    if (i >= total4) return;
    float4 v = ((float4*)x)[i];
    int f = (i * 4) & (F - 1);
    v.x = fmaxf(v.x * sc[f + 0] + sh[f + 0], 0.f);
    v.y = fmaxf(v.y * sc[f + 1] + sh[f + 1], 0.f);
    v.z = fmaxf(v.z * sc[f + 2] + sh[f + 2], 0.f);
    v.w = fmaxf(v.w * sc[f + 3] + sh[f + 3], 0.f);
    ((float4*)x)[i] = v;
}

__global__ __launch_bounds__(256) void out_final_k(
    const float* __restrict__ x, const float* __restrict__ scale,
    const float* __restrict__ shift, float* __restrict__ out, int total)
{
    int i = blockIdx.x * 256 + threadIdx.x;
    if (i >= total) return;
    int f = i & 31;
    out[i] = fmaxf(x[i] * scale[f] + shift[f], 0.f);
}

// ---------------------------------------------------------------------------

extern "C" void kernel_launch(void* const* d_in, const int* in_sizes, int n_in,
                              void* d_out, int out_size, void* d_ws,
                              size_t ws_size, hipStream_t stream)
{
    const float* x   = (const float*)d_in[0];
    const float* W1  = (const float*)d_in[1];
    const float* as1 = (const float*)d_in[2];
    const float* ad1 = (const float*)d_in[3];
    const float* g1  = (const float*)d_in[5];
    const float* be1 = (const float*)d_in[6];
    const float* W2  = (const float*)d_in[7];
    const float* as2 = (const float*)d_in[8];
    const float* ad2 = (const float*)d_in[9];
    const float* g2  = (const float*)d_in[11];
    const float* be2 = (const float*)d_in[12];
    const float* W3  = (const float*)d_in[13];
    const float* as3 = (const float*)d_in[14];
    const float* ad3 = (const float*)d_in[15];
    const float* g3  = (const float*)d_in[17];
    const float* be3 = (const float*)d_in[18];
    const int*   ei  = (const int*)d_in[19];

    const int N  = in_sizes[0] / 128;   // 50000
    const int E  = in_sizes[19] / 2;    // 800000
    const int Et = E + N;
    const int nb = (N + 255) / 256;
    const int NBN = 128;                // bn_stats blocks

    // Workspace layout (4-byte words), packed slots 16B-aligned.
    float* ws = (float*)d_ws;
    size_t off = 0;
    float* Hb  = ws + off;  off += (size_t)N * 64;
    float* AGG = ws + off;  off += (size_t)N * 64;
    float* ES  = ws + off;  off += (size_t)N * 2;
    float* ED  = ws + off;  off += (size_t)N * 2;
    float* SC  = ws + off;  off += 64;
    float* SH  = ws + off;  off += 64;
    float* PS  = ws + off;  off += (size_t)NBN * 64;
    float* PS2 = ws + off;  off += (size_t)NBN * 64;
    int* deg    = (int*)(ws + off);  off += N;        // reused as cursor
    int* rowtmp = (int*)(ws + off);  off += N;
    int* bsum   = (int*)(ws + off);  off += 256;
    int* boff   = (int*)(ws + off);  off += 256;
    int* rowptr = (int*)(ws + off);  off += (size_t)N + 1;
    int* col    = (int*)(ws + off);  off += (size_t)Et;
    off = (off + 3) & ~(size_t)3;                      // 16B align
    float4* PK4 = (float4*)(ws + off);                 // Et float4 slots
    float2* PK2 = (float2*)PK4;                        // reused for layer 3

    const int gemmBlocks64 = (((N + 7) / 8) * 64 + 255) / 256;
    const int gemmBlocks32 = (((N + 7) / 8) * 32 + 255) / 256;
    const int n64Blocks    = (int)(((size_t)N * 64 + 255) / 256);
    const int n32Blocks    = (int)(((size_t)N * 32 + 255) / 256);
    const int edgeBlocks   = (Et + 255) / 256;
    const int nrBlocks64   = (N * 16 + 255) / 256;     // float4 units

    // ---------------- CSR build (once per call) ----------------
    hipMemsetAsync(deg, 0, (size_t)N * sizeof(int), stream);
    deg_k<<<edgeBlocks, 256, 0, stream>>>(ei, deg, E, N);
    scan1_k<<<nb, 256, 0, stream>>>(deg, rowtmp, bsum, N);
    scan2_k<<<1, 256, 0, stream>>>(bsum, boff, nb);
    scan3_k<<<nb, 256, 0, stream>>>(rowtmp, boff, rowptr, N, Et);
    hipMemsetAsync(deg, 0, (size_t)N * sizeof(int), stream);
    scatter_k<<<edgeBlocks, 256, 0, stream>>>(ei, rowptr, deg, col, E, N);

    // ---------------- Layer 1: 128 -> [2 x 32] ----------------
    gemm_attn_k<128, 64, 2><<<gemmBlocks64, 256, 0, stream>>>(x, W1, as1, ad1, Hb, ES, ED, N);
    node_softmax_k<2><<<n64Blocks, 256, 0, stream>>>(rowptr, col, ES, ED, PK4, PK2, N);
    node_gather_k<2><<<n64Blocks, 256, 0, stream>>>(rowptr, PK4, PK2, Hb, AGG, N);
    bn_stats_k<64><<<NBN, 256, 0, stream>>>(AGG, PS, PS2, N);
    bn_final_k<<<1, 64, 0, stream>>>(PS, PS2, g1, be1, SC, SH, N, 64, NBN);

    // ---------------- Layer 2: 64 -> [2 x 32] ----------------
    norm_relu_k<64><<<nrBlocks64, 256, 0, stream>>>(AGG, SC, SH, N * 16);
    gemm_attn_k<64, 64, 2><<<gemmBlocks64, 256, 0, stream>>>(AGG, W2, as2, ad2, Hb, ES, ED, N);
    node_softmax_k<2><<<n64Blocks, 256, 0, stream>>>(rowptr, col, ES, ED, PK4, PK2, N);
    node_gather_k<2><<<n64Blocks, 256, 0, stream>>>(rowptr, PK4, PK2, Hb, AGG, N);
    bn_stats_k<64><<<NBN, 256, 0, stream>>>(AGG, PS, PS2, N);
    bn_final_k<<<1, 64, 0, stream>>>(PS, PS2, g2, be2, SC, SH, N, 64, NBN);

    // ---------------- Layer 3: 64 -> [1 x 32] ----------------
    norm_relu_k<64><<<nrBlocks64, 256, 0, stream>>>(AGG, SC, SH, N * 16);
    gemm_attn_k<64, 32, 1><<<gemmBlocks32, 256, 0, stream>>>(AGG, W3, as3, ad3, Hb, ES, ED, N);
    node_softmax_k<1><<<n32Blocks, 256, 0, stream>>>(rowptr, col, ES, ED, PK4, PK2, N);
    node_gather_k<1><<<n32Blocks, 256, 0, stream>>>(rowptr, PK4, PK2, Hb, AGG, N);
    bn_stats_k<32><<<NBN, 256, 0, stream>>>(AGG, PS, PS2, N);
    bn_final_k<<<1, 32, 0, stream>>>(PS, PS2, g3, be3, SC, SH, N, 32, NBN);
    out_final_k<<<n32Blocks, 256, 0, stream>>>(AGG, SC, SH, (float*)d_out, N * 32);
}